// Round 11
// baseline (452.696 us; speedup 1.0000x reference)
//
#include <hip/hip_runtime.h>
#include <cmath>

#define ROWS 4096      // B*N
#define DIM 768        // D
#define QKV_COLS 2304  // 3*D
#define NHEAD 12
#define HEAD_DIM 64
#define SEQ 2048
#define PADK 72        // LDS row stride (bf16) for VALU-written tiles (Ps)

static constexpr float EPS_F = 1e-8f;

typedef __bf16 bfrag __attribute__((ext_vector_type(8)));   // 8 bf16 = 4 VGPR (MFMA A/B frag)
typedef float  f32x4 __attribute__((ext_vector_type(4)));   // MFMA C/D frag

__device__ __forceinline__ float wave_sum64(float v) {
#pragma unroll
  for (int off = 1; off < 64; off <<= 1) v += __shfl_xor(v, off, 64);
  return v;
}

__device__ __forceinline__ unsigned short f2bf(float f) {
  unsigned u = __float_as_uint(f);
  u += 0x7fffu + ((u >> 16) & 1u);
  return (unsigned short)(u >> 16);
}

// fast tanh(x)/x for x>0:  t=(e-1)/(e+1), e=2^(x*2*log2e);  ->1 as x->0
__device__ __forceinline__ float tanh_over_x(float x) {
  const float e  = __builtin_amdgcn_exp2f(x * 2.8853900817779268f);
  const float th = (e - 1.0f) * __builtin_amdgcn_rcpf(e + 1.0f);
  return (x < 1e-4f) ? 1.0f : th * __builtin_amdgcn_rcpf(x);
}

__device__ __forceinline__ void gl_lds16(const void* g, void* l) {
  __builtin_amdgcn_global_load_lds((const __attribute__((address_space(1))) void*)g,
                                   (__attribute__((address_space(3))) void*)l, 16, 0, 0);
}

// ------------- fused: log0 -> bf16 tangent vectors  +  weight f32->bf16 casts -------------
__global__ __launch_bounds__(256) void log0_conv(const float* __restrict__ x,
                                                 const float* __restrict__ cptr,
                                                 unsigned short* __restrict__ vout,
                                                 const float* __restrict__ wa, int na,
                                                 const float* __restrict__ wb, int nb,
                                                 unsigned short* __restrict__ da,
                                                 unsigned short* __restrict__ db) {
  if (blockIdx.x >= ROWS / 4) {
    const int i = ((blockIdx.x - ROWS / 4) * 256 + threadIdx.x) * 4;
    const float* s;
    unsigned short* d;
    int j;
    if (i < na) { s = wa; d = da; j = i; }
    else { j = i - na; if (j >= nb) return; s = wb; d = db; }
    const float4 v = *(const float4*)(s + j);
    ushort4 o;
    o.x = f2bf(v.x); o.y = f2bf(v.y); o.z = f2bf(v.z); o.w = f2bf(v.w);
    *(ushort4*)(d + j) = o;
    return;
  }
  const int lane = threadIdx.x & 63;
  const int row  = (blockIdx.x << 2) + (threadIdx.x >> 6);
  const float* xr = x + (size_t)row * DIM;
  unsigned short* vr = vout + (size_t)row * DIM;
  float vals[12];
  float ss = 0.f;
#pragma unroll
  for (int i = 0; i < 12; ++i) {
    float t = xr[lane + (i << 6)];
    vals[i] = t;
    ss += t * t;
  }
  ss = wave_sum64(ss);
  const float sc  = sqrtf(cptr[0]);
  const float n   = fmaxf(sqrtf(ss), EPS_F);
  const float scn = sc * n;
  const float t   = fminf(scn, 1.0f - 1e-7f);
  const float ath = 0.34657359027997264f *
                    __builtin_amdgcn_logf((1.0f + t) * __builtin_amdgcn_rcpf(1.0f - t));
  const float f   = (scn < 1e-4f) ? 1.0f : ath * __builtin_amdgcn_rcpf(scn);
#pragma unroll
  for (int i = 0; i < 12; ++i) vr[lane + (i << 6)] = f2bf(vals[i] * f);
}

// ---------------- final exp0: out = tanh(sc*n) * v / (sc*n) ----------------
__global__ __launch_bounds__(256) void exp0_out_kernel(const float* __restrict__ vin,
                                                       const float* __restrict__ cptr,
                                                       float* __restrict__ outp) {
  const int lane = threadIdx.x & 63;
  const int row  = (blockIdx.x << 2) + (threadIdx.x >> 6);
  const float* vr = vin + (size_t)row * DIM;
  float* orow = outp + (size_t)row * DIM;
  float vals[12];
  float ss = 0.f;
#pragma unroll
  for (int i = 0; i < 12; ++i) {
    float t = vr[lane + (i << 6)];
    vals[i] = t;
    ss += t * t;
  }
  ss = wave_sum64(ss);
  const float sc = sqrtf(cptr[0]);
  const float n  = fmaxf(sqrtf(ss), EPS_F);
  const float f  = tanh_over_x(sc * n);
#pragma unroll
  for (int i = 0; i < 12; ++i) orow[lane + (i << 6)] = vals[i] * f;
}

// ---------------- MFMA GEMM NT, prefetch double-buffered (proj GEMM) ----------------
template<int BM, int BN>
__global__ __launch_bounds__(256) void gemm_nt_dbuf(const unsigned short* __restrict__ A,
                                                    const unsigned short* __restrict__ B,
                                                    float* __restrict__ C,
                                                    int M, int Ncols, int K,
                                                    const float* __restrict__ bias) {
  constexpr int FI = BM / 32;
  constexpr int FJ = BN / 32;
  constexpr int CH = BM / 64;
  __shared__ unsigned short As[2][BM * 32];
  __shared__ unsigned short Bs[2][BN * 32];
  const int tid = threadIdx.x;
  const int w = tid >> 6, lane = tid & 63;
  const int lq = lane & 15, quad = lane >> 4;
  const int wr = w >> 1, wc = w & 1;
  const int row0 = blockIdx.y * BM;
  const int col0 = blockIdx.x * BN;
  const int srow  = lane >> 2;
  const int skoff = (lane & 3) << 3;

  f32x4 acc[FI][FJ];
#pragma unroll
  for (int i = 0; i < FI; ++i)
#pragma unroll
    for (int j = 0; j < FJ; ++j) acc[i][j] = (f32x4){0.f, 0.f, 0.f, 0.f};

  auto pf = [&](int k0, int buf) {
#pragma unroll
    for (int c = 0; c < CH; ++c) {
      const int r = c * 64 + w * 16;
      gl_lds16(A + (size_t)(row0 + r + srow) * K + k0 + skoff, &As[buf][r * 32]);
      gl_lds16(B + (size_t)(col0 + r + srow) * K + k0 + skoff, &Bs[buf][r * 32]);
    }
  };

  pf(0, 0);
  const int NIT = K / 32;
  for (int it = 0; it < NIT; ++it) {
    const int buf = it & 1;
    __syncthreads();
    if (it + 1 < NIT) pf((it + 1) * 32, buf ^ 1);

    bfrag af[FI], bfg[FJ];
#pragma unroll
    for (int i = 0; i < FI; ++i)
      af[i] = *(const bfrag*)&As[buf][(wr * (BM / 2) + i * 16 + lq) * 32 + (quad << 3)];
#pragma unroll
    for (int j = 0; j < FJ; ++j)
      bfg[j] = *(const bfrag*)&Bs[buf][(wc * (BN / 2) + j * 16 + lq) * 32 + (quad << 3)];
#pragma unroll
    for (int i = 0; i < FI; ++i)
#pragma unroll
      for (int j = 0; j < FJ; ++j)
        acc[i][j] = __builtin_amdgcn_mfma_f32_16x16x32_bf16(af[i], bfg[j], acc[i][j], 0, 0, 0);
  }

#pragma unroll
  for (int i = 0; i < FI; ++i) {
    const int crow = row0 + wr * (BM / 2) + i * 16 + (quad << 2);
#pragma unroll
    for (int j = 0; j < FJ; ++j) {
      const int col = col0 + wc * (BN / 2) + j * 16 + lq;
      const float bj = bias ? bias[col] : 0.0f;
      float* cp = C + (size_t)crow * Ncols + col;
#pragma unroll
      for (int r = 0; r < 4; ++r)
        cp[(size_t)r * Ncols] = acc[i][j][r] + bj;
    }
  }
}

// ------------- fused QKV GEMM: 128x128 m97-style + exp0/norm/V-transpose epilogue -------
// Also zeroes the flash pair-counters (block (0,0)) -- visible to flash at kernel boundary.
__global__ __launch_bounds__(256) void gemm_qkv_fused(const unsigned short* __restrict__ A,
                                                      const unsigned short* __restrict__ B,
                                                      const float* __restrict__ cptr,
                                                      unsigned short* __restrict__ qh,
                                                      unsigned short* __restrict__ kh,
                                                      unsigned short* __restrict__ vth,
                                                      float* __restrict__ qnA,
                                                      float* __restrict__ qnB,
                                                      float* __restrict__ knA,
                                                      float* __restrict__ knB,
                                                      unsigned* __restrict__ cnt) {
  if (blockIdx.x == 0 && blockIdx.y == 0) {
    for (int i = threadIdx.x; i < 768; i += 256) cnt[i] = 0;
  }
  __shared__ unsigned short As[2][128 * 32];
  __shared__ unsigned short Bs[2][128 * 32];
  const int tid = threadIdx.x;
  const int w = tid >> 6, lane = tid & 63;
  const int lq = lane & 15, quad = lane >> 4;
  const int wr = w >> 1, wc = w & 1;
  const int row0 = blockIdx.y << 7;
  const int col0 = blockIdx.x << 7;
  const int srow  = lane >> 2;
  const int skoff = (lane & 3) << 3;

  f32x4 acc[4][4];
#pragma unroll
  for (int i = 0; i < 4; ++i)
#pragma unroll
    for (int j = 0; j < 4; ++j) acc[i][j] = (f32x4){0.f, 0.f, 0.f, 0.f};

  auto pf = [&](int k0, int buf) {
#pragma unroll
    for (int c = 0; c < 2; ++c) {
      const int r = c * 64 + w * 16;
      gl_lds16(A + (size_t)(row0 + r + srow) * DIM + k0 + skoff, &As[buf][r * 32]);
      gl_lds16(B + (size_t)(col0 + r + srow) * DIM + k0 + skoff, &Bs[buf][r * 32]);
    }
  };

  pf(0, 0);
  for (int it = 0; it < DIM / 32; ++it) {
    const int buf = it & 1;
    __syncthreads();
    if (it + 1 < DIM / 32) pf((it + 1) * 32, buf ^ 1);

    bfrag af[4], bfg[4];
#pragma unroll
    for (int i = 0; i < 4; ++i)
      af[i] = *(const bfrag*)&As[buf][((wr << 6) + (i << 4) + lq) * 32 + (quad << 3)];
#pragma unroll
    for (int j = 0; j < 4; ++j)
      bfg[j] = *(const bfrag*)&Bs[buf][((wc << 6) + (j << 4) + lq) * 32 + (quad << 3)];
#pragma unroll
    for (int i = 0; i < 4; ++i)
#pragma unroll
      for (int j = 0; j < 4; ++j)
        acc[i][j] = __builtin_amdgcn_mfma_f32_16x16x32_bf16(af[i], bfg[j], acc[i][j], 0, 0, 0);
  }

  // ---- fused epilogue ----
  const int colw = col0 + (wc << 6);
  const int seg  = colw / DIM;                // 0=q, 1=k, 2=v
  const int hh   = (colw % DIM) >> 6;
  const int rowb = row0 + (wr << 6);

  if (seg == 2) {
#pragma unroll
    for (int i = 0; i < 4; ++i)
#pragma unroll
      for (int r = 0; r < 4; ++r) {
        const int rowg = rowb + (i << 4) + (quad << 2) + r;
        const int bh = (rowg >> 11) * NHEAD + hh;
        const int n_ = rowg & 2047;
#pragma unroll
        for (int j = 0; j < 4; ++j)
          vth[((size_t)bh * HEAD_DIM + (j << 4) + lq) * SEQ + n_] = f2bf(acc[i][j][r]);
      }
  } else {
    unsigned short* dst = seg ? kh : qh;
    float* nA = seg ? knA : qnA;
    float* nB = seg ? knB : qnB;
    const float sc = sqrtf(cptr[0]);
#pragma unroll
    for (int i = 0; i < 4; ++i)
#pragma unroll
      for (int r = 0; r < 4; ++r) {
        float ss = acc[i][0][r] * acc[i][0][r];
        ss = fmaf(acc[i][1][r], acc[i][1][r], ss);
        ss = fmaf(acc[i][2][r], acc[i][2][r], ss);
        ss = fmaf(acc[i][3][r], acc[i][3][r], ss);
        ss += __shfl_xor(ss, 1, 64);
        ss += __shfl_xor(ss, 2, 64);
        ss += __shfl_xor(ss, 4, 64);
        ss += __shfl_xor(ss, 8, 64);
        const float nn = fmaxf(sqrtf(ss), EPS_F);
        const float f  = tanh_over_x(sc * nn);
        const int rowg = rowb + (i << 4) + (quad << 2) + r;
        const int bh = (rowg >> 11) * NHEAD + hh;
        const int n_ = rowg & 2047;
        unsigned short* rp = dst + ((size_t)bh * SEQ + n_) * HEAD_DIM;
#pragma unroll
        for (int j = 0; j < 4; ++j)
          rp[(j << 4) + lq] = f2bf(acc[i][j][r] * f);
        if (lq == 0) {
          const float nrm = ss * f * f;
          nA[(size_t)bh * SEQ + n_] = nrm;
          nB[(size_t)bh * SEQ + n_] = 1.0f / (1.0f - fminf(nrm, 0.99f));
        }
      }
  }
}

// ------------- MFMA flash attention: key-split pairs, 6 blocks/CU, inline combine -------
// grid 1536: g = flat%768 -> (bh=g%24 XCD-clustered, qt=g/24); kg = flat/768 picks key half
// (16 rounds of 64 keys). Single-buffered Ks/Vt (25.6 KB LDS -> 6 blocks/CU = 24 waves/CU),
// 2 barriers/round. Partial (O fp32, l) -> ws; second finisher of each pair combines via
// device-scope atomic ticket + threadfences, normalizes, writes bf16 attn_out.
__global__ __launch_bounds__(256) void flash_mfma(const unsigned short* __restrict__ qh,
                                                  const unsigned short* __restrict__ kh,
                                                  const unsigned short* __restrict__ vth,
                                                  const float* __restrict__ qnA,
                                                  const float* __restrict__ qnB,
                                                  const float* __restrict__ knA,
                                                  const float* __restrict__ knB,
                                                  float* __restrict__ partO,
                                                  float* __restrict__ partL,
                                                  unsigned* __restrict__ cnt,
                                                  unsigned short* __restrict__ attn_out) {
  const int flat = blockIdx.x;
  const int kg   = flat / 768;
  const int g    = flat - kg * 768;
  const int bhid = g % 24;
  const int qt   = g / 24;
  const int h = bhid % NHEAD, b = bhid / NHEAD;
  const int bh = b * NHEAD + h;
  const int tid = threadIdx.x;
  const int w = tid >> 6, lane = tid & 63;
  const int lq = lane & 15, quad = lane >> 4;

  __shared__ unsigned short Ks[64 * 64];   // swizzled [key][hd]
  __shared__ unsigned short Vt[64 * 64];   // swizzled [d][key]
  __shared__ unsigned short Ps[64 * PADK]; // [q][key], stride 72
  __shared__ unsigned oldv;

  const unsigned short* qbase = qh + ((size_t)bh * SEQ + (size_t)qt * 64) * HEAD_DIM;
  const float* knAb = knA + (size_t)bh * SEQ;
  const float* knBb = knB + (size_t)bh * SEQ;

  const int srow = tid >> 3, spos = tid & 7;
  const int sB = spos ^ (srow & 7);
  const char* kgsrc = (const char*)(kh + (size_t)bh * SEQ * HEAD_DIM) + (size_t)srow * 128 + sB * 16;
  const char* vgsrc = (const char*)(vth + (size_t)bh * HEAD_DIM * SEQ) + (size_t)srow * 4096 + sB * 16;

  // Q fragments (B operand in S^T): frag[l][j] = Q[q = w*16+(l&15)][hd = khf*32+quad*8+j]
  bfrag aq[2];
#pragma unroll
  for (int khf = 0; khf < 2; ++khf)
    aq[khf] = *(const bfrag*)(qbase + (size_t)(w * 16 + lq) * HEAD_DIM + khf * 32 + quad * 8);

  const float qnS = qnA[(size_t)bh * SEQ + qt * 64 + w * 16 + lq];
  const float rqS = 2.0f * qnB[(size_t)bh * SEQ + qt * 64 + w * 16 + lq];

  bfrag ones;
#pragma unroll
  for (int j = 0; j < 8; ++j) ones[j] = (__bf16)1.0f;

  f32x4 oacc[4];
  f32x4 lacc = (f32x4){0.f, 0.f, 0.f, 0.f};
#pragma unroll
  for (int d = 0; d < 4; ++d) oacc[d] = (f32x4){0.f, 0.f, 0.f, 0.f};
  const int swz = lq & 7;

  const int kt0 = kg << 4;
  for (int kt = kt0; kt < kt0 + 16; ++kt) {
    const int key0 = kt * 64;
    __syncthreads();  // all waves done reading prev round's tiles
    {
      const char* kp = kgsrc + (size_t)kt * 8192;  // 64 keys * 128B
      const char* vp = vgsrc + (size_t)kt * 128;   // 64 keys * 2B per d-row
      gl_lds16(kp,          (char*)Ks + w * 1024);
      gl_lds16(kp + 4096,   (char*)Ks + 4096 + w * 1024);
      gl_lds16(vp,          (char*)Vt + w * 1024);
      gl_lds16(vp + 131072, (char*)Vt + 4096 + w * 1024);
    }
    // kn norms direct from global (L2-hot), drained with the stage at the barrier
    f32x4 kna[4], knr[4];
#pragma unroll
    for (int st = 0; st < 4; ++st) {
      kna[st] = *(const f32x4*)(knAb + key0 + st * 16 + (quad << 2));
      knr[st] = *(const f32x4*)(knBb + key0 + st * 16 + (quad << 2));
    }
    __syncthreads();  // tiles ready

    // ---- S^T strip [64k x 16q] = K·Q^T via MFMA ----
    f32x4 s[4];
#pragma unroll
    for (int st = 0; st < 4; ++st) s[st] = (f32x4){0.f, 0.f, 0.f, 0.f};
#pragma unroll
    for (int khf = 0; khf < 2; ++khf)
#pragma unroll
      for (int st = 0; st < 4; ++st) {
        const bfrag ak = *(const bfrag*)&Ks[(st * 16 + lq) * 64 + (((khf << 2) + quad) ^ swz) * 8];
        s[st] = __builtin_amdgcn_mfma_f32_16x16x32_bf16(ak, aq[khf], s[st], 0, 0, 0);
      }

    // ---- w = (inner + sqrt(inner^2-1))^(-1/8); pack 4 keys via v_perm ----
#pragma unroll
    for (int st = 0; st < 4; ++st) {
      unsigned u[4];
#pragma unroll
      for (int i = 0; i < 4; ++i) {
        float tt = fmaf(-2.0f, s[st][i], qnS + kna[st][i]);
        tt = fmaxf(tt, 0.0f);
        const float inner = fmaf(tt, rqS * knr[st][i], 1.0f);
        const float root = __builtin_amdgcn_sqrtf(fmaf(inner, inner, -1.0f));
        const float wgt = __builtin_amdgcn_exp2f(-0.125f * __builtin_amdgcn_logf(inner + root));
        u[i] = __float_as_uint(wgt);
      }
      uint2 pk;
      pk.x = __builtin_amdgcn_perm(u[1], u[0], 0x07060302u);
      pk.y = __builtin_amdgcn_perm(u[3], u[2], 0x07060302u);
      *(uint2*)&Ps[(w * 16 + lq) * PADK + st * 16 + quad * 4] = pk;
    }

    // ---- O += P·V ; l += P·1 (intra-wave Ps, DS in-order: no barrier) ----
#pragma unroll
    for (int khf = 0; khf < 2; ++khf) {
      const bfrag ap = *(const bfrag*)&Ps[(w * 16 + lq) * PADK + khf * 32 + quad * 8];
      lacc = __builtin_amdgcn_mfma_f32_16x16x32_bf16(ap, ones, lacc, 0, 0, 0);
#pragma unroll
      for (int d = 0; d < 4; ++d) {
        const bfrag bv = *(const bfrag*)&Vt[(d * 16 + lq) * 64 + (((khf << 2) + quad) ^ swz) * 8];
        oacc[d] = __builtin_amdgcn_mfma_f32_16x16x32_bf16(ap, bv, oacc[d], 0, 0, 0);
      }
    }
  }

  // ---- write partial (O fp32, l), ticket; second finisher combines + stores ----
  float* po = partO + (size_t)flat * 4096;
  float* pl = partL + (size_t)flat * 64;
#pragma unroll
  for (int d = 0; d < 4; ++d)
#pragma unroll
    for (int i = 0; i < 4; ++i)
      po[(size_t)(w * 16 + quad * 4 + i) * 64 + d * 16 + lq] = oacc[d][i];
  if (lq == 0) {
#pragma unroll
    for (int i = 0; i < 4; ++i) pl[w * 16 + quad * 4 + i] = lacc[i];
  }
  __threadfence();                       // release: partial visible before ticket
  if (tid == 0) oldv = atomicAdd(&cnt[g], 1u);
  __syncthreads();
  if (oldv == 1) {
    __threadfence();                     // acquire: other block's partial now safe to read
    const int other = kg ? (flat - 768) : (flat + 768);
    const float* qo = partO + (size_t)other * 4096;
    const float* ql = partL + (size_t)other * 64;
    float rl4[4];
#pragma unroll
    for (int i = 0; i < 4; ++i)
      rl4[i] = __builtin_amdgcn_rcpf(lacc[i] + ql[w * 16 + quad * 4 + i]);
    unsigned short* ob = attn_out + ((size_t)b * SEQ + (size_t)qt * 64 + w * 16) * DIM + h * HEAD_DIM;
#pragma unroll
    for (int d = 0; d < 4; ++d)
#pragma unroll
      for (int i = 0; i < 4; ++i) {
        const float ot = oacc[d][i] + qo[(size_t)(w * 16 + quad * 4 + i) * 64 + d * 16 + lq];
        ob[(size_t)(quad * 4 + i) * DIM + d * 16 + lq] = f2bf(ot * rl4[i]);
      }
  }
}

extern "C" void kernel_launch(void* const* d_in, const int* in_sizes, int n_in,
                              void* d_out, int out_size, void* d_ws, size_t ws_size,
                              hipStream_t stream) {
  const float* x      = (const float*)d_in[0];
  const float* w_qkv  = (const float*)d_in[1];
  const float* w_proj = (const float*)d_in[2];
  const float* b_proj = (const float*)d_in[3];
  const float* curv   = (const float*)d_in[4];
  float* outp = (float*)d_out;

  float* ws = (float*)d_ws;
  // region A (bf16 3,145,728): v_tan_bf during QKV GEMM; attn_bf during proj GEMM
  unsigned short* v_tan_bf = (unsigned short*)ws;
  unsigned short* attn_bf  = (unsigned short*)ws;
  float* v_out = ws + 1572864;                         // 3,145,728 f
  unsigned short* qh  = (unsigned short*)(v_out + 3145728);
  unsigned short* kh  = qh + 3145728;
  unsigned short* vth = kh + 3145728;
  unsigned short* wqkv_bf  = vth + 3145728;            // 1,769,472 bf16
  unsigned short* wproj_bf = wqkv_bf + 1769472;        // 589,824 bf16
  float* qnA = (float*)(wproj_bf + 589824);            // 49,152 f each
  float* qnB = qnA + 49152;
  float* knA = qnB + 49152;
  float* knB = knA + 49152;
  float* partO = knB + 49152;                          // 1536*4096 f = 6,291,456 f
  float* partL = partO + 6291456;                      // 1536*64 f
  unsigned* cnt = (unsigned*)(partL + 98304);          // 768 u32

  log0_conv<<<dim3(ROWS / 4 + 2304), dim3(256), 0, stream>>>(
      x, curv, v_tan_bf, w_qkv, 1769472, w_proj, 589824, wqkv_bf, wproj_bf);
  gemm_qkv_fused<<<dim3(QKV_COLS / 128, ROWS / 128), dim3(256), 0, stream>>>(
      v_tan_bf, wqkv_bf, curv, qh, kh, vth, qnA, qnB, knA, knB, cnt);
  flash_mfma<<<dim3(1536), dim3(256), 0, stream>>>(qh, kh, vth, qnA, qnB, knA, knB,
                                                   partO, partL, cnt, attn_bf);
  gemm_nt_dbuf<64, 64><<<dim3(DIM / 64, ROWS / 64), dim3(256), 0, stream>>>(
      attn_bf, wproj_bf, v_out, ROWS, DIM, DIM, b_proj);
  exp0_out_kernel<<<dim3(ROWS / 4), dim3(256), 0, stream>>>(v_out, curv, outp);
}